// Round 10
// baseline (243.308 us; speedup 1.0000x reference)
//
#include <hip/hip_runtime.h>
#include <hip/hip_fp16.h>

#define DM 128
#define NHEADS 8
#define MAXDEG 64
#define SROW 136       // LDS row stride in halves: 128+8 pad (2-way bank alias = free)
#define WCONV_BLOCKS 8

typedef _Float16 half8 __attribute__((ext_vector_type(8)));
typedef _Float16 half2v __attribute__((ext_vector_type(2)));
typedef float floatx4 __attribute__((ext_vector_type(4)));

union H8 { half8 v; half2v h2[4]; _Float16 h[8]; };

__device__ inline half8 cvt8(const float4 f0, const float4 f1) {
  return half8{(_Float16)f0.x, (_Float16)f0.y, (_Float16)f0.z, (_Float16)f0.w,
               (_Float16)f1.x, (_Float16)f1.y, (_Float16)f1.z, (_Float16)f1.w};
}

// ========== fused: proj GEMM [0,P) + CSR build [P,P+C) + Wo fp16 convert [P+C,P+C+8) ==========
// (R5 structure — measured 76 us.) proj: X(Mx128,f32) @ Wcat^T(576x128), inline f32->f16 W
// staging, one block = 128 M-rows x all 576 N-cols (9 chunks of 64). X read exactly once.
// chunk pairs: 0,1->Q  2,3->K(KV lo)  4,5->V(KV hi)  6,7->sigmoid gate  8->bias cols 512..519
// CSR blocks: 8192 edges each, 32 edges/thread batched 8-deep (measured-best config).
__global__ __launch_bounds__(256) void proj_csr(
    const float* __restrict__ X, const float* __restrict__ Wqkv,
    const float* __restrict__ Wgate, const float* __restrict__ wbias,
    const float* __restrict__ b_gate, const float* __restrict__ Wo,
    const int* __restrict__ nsrc, const int* __restrict__ ndst,
    int* __restrict__ cnt, int* __restrict__ csr_dst,
    _Float16* __restrict__ Q, _Float16* __restrict__ KV,
    _Float16* __restrict__ gate, float* __restrict__ bias,
    _Float16* __restrict__ Wo16,
    int M, int E, int P, int C) {
  __shared__ _Float16 As[128 * SROW];
  __shared__ _Float16 Bs[64 * SROW];
  int tid = threadIdx.x;
  int bid = blockIdx.x;

  if (bid >= P + C) {
    // ---------------- Wo fp32 -> fp16 role: 8 blocks x 2048 elements ----------------
    int u = (bid - P - C) * 2048 + tid * 8;   // 8*256*8 = 16384 = 128*128
    const float4* s = (const float4*)(Wo + u);
    *(half8*)(Wo16 + u) = cvt8(s[0], s[1]);
    return;
  }

  if (bid >= P) {
    // ---------------- CSR build role: 32 edges/thread, batch-8 ----------------
    int ebase = (bid - P) * 8192;
    for (int g = 0; g < 4; g++) {
      int s[8], d[8];
#pragma unroll
      for (int j = 0; j < 8; j++) {
        int e = ebase + (g * 8 + j) * 256 + tid;
        s[j] = (e < E) ? nsrc[e] : -1;
        d[j] = (e < E) ? ndst[e] : 0;
      }
#pragma unroll
      for (int j = 0; j < 8; j++) {
        if (s[j] >= 0) {
          int p = atomicAdd(&cnt[s[j]], 1);
          if (p < MAXDEG) csr_dst[(size_t)s[j] * MAXDEG + p] = d[j];
        }
      }
    }
    return;
  }

  // ---------------- projection GEMM role ----------------
  int m0 = bid * 128;

  // stage A (fp32 -> fp16): 128 rows x 128 cols
#pragma unroll
  for (int i = 0; i < 4; i++) {
    int u = tid + i * 256;           // 0..1023
    int r = u >> 3;
    int cc = (u & 7) * 16;
    int gr = m0 + r;
    float4 f0, f1, f2, f3;
    if (gr < M) {
      const float4* src = (const float4*)(X + (size_t)gr * 128 + cc);
      f0 = src[0]; f1 = src[1]; f2 = src[2]; f3 = src[3];
    } else {
      f0 = f1 = f2 = f3 = make_float4(0.f, 0.f, 0.f, 0.f);
    }
    *(half8*)(As + r * SROW + cc) = cvt8(f0, f1);
    *(half8*)(As + r * SROW + cc + 8) = cvt8(f2, f3);
  }

  int wid = tid >> 6, lane = tid & 63;
  int quad = lane >> 4, l16 = lane & 15;
  int mw = wid * 32;                 // wave owns 32 M-rows

  for (int c = 0; c < 9; c++) {
    __syncthreads();                 // previous chunk's Bs readers done (orders A on c=0)
#pragma unroll
    for (int i = 0; i < 4; i++) {
      int u = tid + i * 256;         // 0..1023
      int r = u >> 4;                // 0..63
      int cc = (u & 15) * 8;
      int grow = c * 64 + r;
      const float* src = nullptr;
      if (grow < 384)      src = Wqkv + (size_t)grow * 128 + cc;
      else if (grow < 512) src = Wgate + (size_t)(grow - 384) * 128 + cc;
      else if (grow < 520) src = wbias + (size_t)(grow - 512) * 128 + cc;
      half8 h = {};
      if (src) h = cvt8(((const float4*)src)[0], ((const float4*)src)[1]);
      *(half8*)(Bs + r * SROW + cc) = h;
    }
    __syncthreads();

    floatx4 acc[2][4] = {};
#pragma unroll
    for (int kc = 0; kc < 4; kc++) {
      int ko = kc * 32 + quad * 8;
      half8 a0 = *(const half8*)(As + (mw + l16) * SROW + ko);
      half8 a1 = *(const half8*)(As + (mw + 16 + l16) * SROW + ko);
      half8 b[4];
#pragma unroll
      for (int ni = 0; ni < 4; ni++)
        b[ni] = *(const half8*)(Bs + (ni * 16 + l16) * SROW + ko);
#pragma unroll
      for (int ni = 0; ni < 4; ni++) {
        acc[0][ni] = __builtin_amdgcn_mfma_f32_16x16x32_f16(a0, b[ni], acc[0][ni], 0, 0, 0);
        acc[1][ni] = __builtin_amdgcn_mfma_f32_16x16x32_f16(a1, b[ni], acc[1][ni], 0, 0, 0);
      }
    }

    if (c == 8) {                    // bias chunk: only cols 512..519 real
      if (l16 < 8) {
#pragma unroll
        for (int mi = 0; mi < 2; mi++)
#pragma unroll
          for (int r = 0; r < 4; r++) {
            int row = m0 + mw + mi * 16 + quad * 4 + r;
            if (row < M) bias[(size_t)row * 8 + l16] = acc[mi][0][r];
          }
      }
    } else {
      int reg = c >> 1;              // 0:Q 1:K 2:V 3:gate (wave-uniform)
#pragma unroll
      for (int mi = 0; mi < 2; mi++) {
#pragma unroll
        for (int ni = 0; ni < 4; ni++) {
          int colL = (c & 1) * 64 + ni * 16 + l16;   // 0..127 within region
#pragma unroll
          for (int r = 0; r < 4; r++) {
            int row = m0 + mw + mi * 16 + quad * 4 + r;
            if (row >= M) continue;
            float v = acc[mi][ni][r];
            if (reg == 0)      Q[(size_t)row * 128 + colL] = (_Float16)v;
            else if (reg == 1) KV[(size_t)row * 256 + colL] = (_Float16)v;
            else if (reg == 2) KV[(size_t)row * 256 + 128 + colL] = (_Float16)v;
            else gate[(size_t)row * 128 + colL] =
                   (_Float16)(1.0f / (1.0f + __expf(-(v + b_gate[colL]))));
          }
        }
      }
    }
  }
}

// ===== fused attention + output epilogue: 4 waves = 4 nodes/block (R5 attn loop) =====
// attn: quarter-wave per edge; lane = qtr*16 + l16 owns channels [l16*8,+8); head = l16>>1;
// fdot2 score dot + prefetch depth 2 (measured-best variant, R5).
// epilogue: gated rows -> Gs LDS tile (rows 0-3; rows 4-15 garbage, harmless: MFMA D-rows
// are independent per A-row), one barrier, out(4x128) = Gs @ Wo16^T via MFMA -> f32 stores.
__global__ __launch_bounds__(256) void attn_out(
    const int* __restrict__ cnt, const int* __restrict__ csr_dst,
    const _Float16* __restrict__ Q, const _Float16* __restrict__ KV,
    const float* __restrict__ bias, const _Float16* __restrict__ gate,
    const _Float16* __restrict__ Wo16, float* __restrict__ out, int N) {
  __shared__ _Float16 Gs[16 * SROW];
  int wave = threadIdx.x >> 6, lane = threadIdx.x & 63;
  int n0 = blockIdx.x * 4;
  int n = n0 + wave;
  bool active = n < N;
  int n_eff = active ? n : 0;
  int qtr = lane >> 4, l16 = lane & 15;
  int ch0 = l16 * 8;

  int deg = active ? cnt[n_eff] : 0;
  if (deg > MAXDEG) deg = MAXDEG;

  int dstv = csr_dst[(size_t)n_eff * MAXDEG + lane];   // coalesced; garbage beyond deg

  H8 qu; qu.v = *(const half8*)(Q + (size_t)n_eff * DM + ch0);
  float bias_h = bias[(size_t)n_eff * NHEADS + (l16 >> 1)];

  float acc[8] = {};
  float den = 0.f;
  int iters = (deg + 3) >> 2;        // 4 edges per iteration (one per quarter-wave)

  H8 k0, v0, k1, v1;
  k0.v = half8{}; v0.v = half8{}; k1.v = half8{}; v1.v = half8{};
  bool b0 = false, b1 = false;
  if (0 < iters) {
    int e = qtr;
    b0 = e < deg;
    int d = __shfl(dstv, e);
    d = b0 ? d : 0;
    const _Float16* kvp = KV + (size_t)d * 256 + ch0;
    k0.v = *(const half8*)kvp;
    v0.v = *(const half8*)(kvp + 128);
  }
  if (1 < iters) {
    int e = 4 + qtr;
    b1 = e < deg;
    int d = __shfl(dstv, e);
    d = b1 ? d : 0;
    const _Float16* kvp = KV + (size_t)d * 256 + ch0;
    k1.v = *(const half8*)kvp;
    v1.v = *(const half8*)(kvp + 128);
  }

  for (int it = 0; it < iters; it++) {
    H8 k2, v2; k2.v = half8{}; v2.v = half8{};
    bool b2 = false;
    if (it + 2 < iters) {            // wave-uniform branch
      int e = (it + 2) * 4 + qtr;    // <= 63 since deg <= 64
      b2 = e < deg;
      int d = __shfl(dstv, e);
      d = b2 ? d : 0;
      const _Float16* kvp = KV + (size_t)d * 256 + ch0;
      k2.v = *(const half8*)kvp;
      v2.v = *(const half8*)(kvp + 128);
    }
    float p = 0.f;
#pragma unroll
    for (int j = 0; j < 4; j++)
      p = __builtin_amdgcn_fdot2(qu.h2[j], k0.h2[j], p, false);
    p += __shfl_xor(p, 1);           // 16-channel head dot
    float w = __expf(p * 0.25f + bias_h);   // scale=1/sqrt(16); scores O(10), fp32-safe
    if (!b0) w = 0.f;
    den += w;
#pragma unroll
    for (int j = 0; j < 8; j++) acc[j] = fmaf(w, (float)v0.h[j], acc[j]);
    k0 = k1; v0 = v1; b0 = b1;
    k1 = k2; v1 = v2; b1 = b2;
  }
  // combine the four quarter-wave partials (butterfly)
#pragma unroll
  for (int j = 0; j < 8; j++) {
    acc[j] += __shfl_xor(acc[j], 16);
    acc[j] += __shfl_xor(acc[j], 32);
  }
  den += __shfl_xor(den, 16);
  den += __shfl_xor(den, 32);

  if (qtr == 0) {                    // lanes 0..15 hold the full 128-vector
    float inv = 1.0f / (den + 1e-12f);
    H8 gv; gv.v = *(const half8*)(gate + (size_t)n_eff * DM + ch0);
    half8 o;
#pragma unroll
    for (int j = 0; j < 8; j++) o[j] = (_Float16)(acc[j] * inv * (float)gv.h[j]);
    *(half8*)(Gs + wave * SROW + ch0) = o;
  }

  __syncthreads();

  // epilogue: out(4x128) = Gs(rows 0-3) @ Wo16^T. Wave covers cols [wave*32, +32).
  // A-frag rows m=l16 (rows 4-15 garbage -> D rows 4-15 garbage, discarded).
  floatx4 oc[2] = {};
#pragma unroll
  for (int kc = 0; kc < 4; kc++) {
    int ko = kc * 32 + qtr * 8;
    half8 a = *(const half8*)(Gs + l16 * SROW + ko);
#pragma unroll
    for (int ni = 0; ni < 2; ni++) {
      half8 b = *(const half8*)(Wo16 + (size_t)(wave * 32 + ni * 16 + l16) * 128 + ko);
      oc[ni] = __builtin_amdgcn_mfma_f32_16x16x32_f16(a, b, oc[ni], 0, 0, 0);
    }
  }
  if (qtr == 0) {                    // D rows 0..3 live in quad 0 (row = qtr*4 + r)
#pragma unroll
    for (int ni = 0; ni < 2; ni++) {
      int col = wave * 32 + ni * 16 + l16;
#pragma unroll
      for (int r = 0; r < 4; r++) {
        int row = n0 + r;
        if (row < N) out[(size_t)row * 128 + col] = oc[ni][r];
      }
    }
  }
}

extern "C" void kernel_launch(void* const* d_in, const int* in_sizes, int n_in,
                              void* d_out, int out_size, void* d_ws, size_t ws_size,
                              hipStream_t stream) {
  const float* X     = (const float*)d_in[0];
  const float* Wqkv  = (const float*)d_in[1];
  const float* wbias = (const float*)d_in[2];
  const float* Wgate = (const float*)d_in[3];
  const float* bgate = (const float*)d_in[4];
  const float* Wo    = (const float*)d_in[5];
  const int*   nsrc  = (const int*)d_in[6];
  const int*   ndst  = (const int*)d_in[7];
  int N = in_sizes[0] / 128;
  int E = in_sizes[6];
  float* out = (float*)d_out;

  char* p = (char*)d_ws;
  _Float16* Q16     = (_Float16*)p; p += (size_t)N * 128 * sizeof(_Float16);
  _Float16* KV16    = (_Float16*)p; p += (size_t)N * 256 * sizeof(_Float16);
  _Float16* gate16  = (_Float16*)p; p += (size_t)N * 128 * sizeof(_Float16);
  float* bias       = (float*)p;    p += (size_t)N * 8 * sizeof(float);
  _Float16* Wo16    = (_Float16*)p; p += (size_t)128 * 128 * sizeof(_Float16);
  int* cnt          = (int*)p;      p += (size_t)N * sizeof(int);
  int* csr_dst      = (int*)p;      p += (size_t)N * MAXDEG * sizeof(int);

  hipMemsetAsync(cnt, 0, (size_t)N * sizeof(int), stream);

  int P = (N + 127) / 128;                 // proj blocks
  int C = (E + 8191) / 8192;               // csr blocks (32 edges/thread, batch-8)
  proj_csr<<<P + C + WCONV_BLOCKS, 256, 0, stream>>>(
      X, Wqkv, Wgate, wbias, bgate, Wo, nsrc, ndst,
      cnt, csr_dst, Q16, KV16, gate16, bias, Wo16, N, E, P, C);

  attn_out<<<(N + 3) / 4, 256, 0, stream>>>(cnt, csr_dst, Q16, KV16, bias,
                                            gate16, Wo16, out, N);
}